// Round 8
// baseline (415.854 us; speedup 1.0000x reference)
//
#include <hip/hip_runtime.h>

using u16 = unsigned short;
using u32 = unsigned int;

typedef __bf16 bf16x8 __attribute__((ext_vector_type(8)));
typedef float  f32x4  __attribute__((ext_vector_type(4)));

#define NPOS   225          // 15*15 valid positions
#define NT     15           // row-tiles; p' = i*16 + j (j<15 valid)
#define ROWP   136          // padded LDS row stride in ushorts (272B, 16B-aligned)
#define A_ROWS 289          // 17*17 haloed
#define B_ROWS 241          // 240 p' rows + 1 guard
#define A_ELEMS (A_ROWS*ROWP)            // 39304 u16
#define B_ELEMS (B_ROWS*ROWP)            // 32776 u16
#define LDS_BYTES ((A_ELEMS + B_ELEMS)*2)  // 144160 B < 160 KiB
#define RSTRIDE17 (17*ROWP)              // 2312

// ---- workspace layout ----
// floats [0..768): dconv0 weights transposed [k=c*3+t][o]
// then bf16 (u16) region, offsets in u16 units:
#define WA_PER_L 49152      // per dconv layer: [8 ot][12 f=t*4+kb][64 lane][8]
#define WP_OFF   (4*WA_PER_L)          // 196608 ; 6 x [8 ot][4 kb][64][8]
#define WP_PER   16384
#define WF_OFF   (WP_OFF + 6*WP_PER)   // 294912 ; [4 ot][4 kb][64][8]
#define W_U16_TOTAL (WF_OFF + 8192)    // 303104

__device__ __forceinline__ float bflo(u32 q){ return __uint_as_float(q << 16); }
__device__ __forceinline__ float bfhi(u32 q){ return __uint_as_float(q & 0xffff0000u); }
__device__ __forceinline__ u16 f2bf(float f){
  u32 u = __float_as_uint(f);
  return (u16)((u + 0x7fffu + ((u >> 16) & 1u)) >> 16);   // RNE (prep kernel only)
}
__device__ __forceinline__ u32 packbf(float a, float b){
  union { __bf16 h[2]; u32 u; } r;
  r.h[0] = (__bf16)a; r.h[1] = (__bf16)b;   // native cast -> v_cvt_pk_bf16_f32
  return r.u;
}
__device__ __forceinline__ float silu_f(float x){
  return x * __builtin_amdgcn_rcpf(1.f + __expf(-x));
}
__device__ __forceinline__ f32x4 mfma16(bf16x8 a, bf16x8 b, f32x4 c){
  return __builtin_amdgcn_mfma_f32_16x16x32_bf16(a, b, c, 0, 0, 0);
}

// ---- weight prep: fp32 transpose for dconv0 + bf16 per-lane fragment swizzle ----
__global__ void prep_w(const float* __restrict__ d0w, const float* __restrict__ rdw,
                       const float* __restrict__ rpw, const float* __restrict__ c1w,
                       const float* __restrict__ c2w, const float* __restrict__ fw,
                       float* __restrict__ ws)
{
  u16* wsb = (u16*)(ws + 768);
  const int total = 768 + W_U16_TOTAL;
  for (int idx = blockIdx.x*blockDim.x + threadIdx.x; idx < total; idx += gridDim.x*blockDim.x){
    if (idx < 768){                      // dconv0 fp32: [6][128] <- [128][2][3]
      int k = idx >> 7, o = idx & 127;
      ws[idx] = d0w[o*6 + k];
      continue;
    }
    int e = idx - 768;
    float v;
    if (e < WP_OFF){                     // res dconv frags
      int L = e / WA_PER_L, r = e % WA_PER_L;
      int w = r / 6144, r2 = r % 6144;
      int t = r2 >> 11, r3 = r2 & 2047;  // t stride 2048
      int kb = r3 >> 9, r4 = r3 & 511;
      int l = r4 >> 3, j = r4 & 7;
      int o = w*16 + (l & 15);
      int c = kb*32 + ((l >> 4) << 3) + j;
      v = rdw[((L*128 + o)*128 + c)*3 + t];
    } else if (e < WF_OFF){              // pointwise frags (res0..3, c1, c2)
      int t2 = e - WP_OFF;
      int i = t2 / WP_PER, r = t2 % WP_PER;
      int w = r >> 11, r2 = r & 2047;
      int kb = r2 >> 9, r3 = r2 & 511;
      int l = r3 >> 3, j = r3 & 7;
      int o = w*16 + (l & 15);
      int c = kb*32 + ((l >> 4) << 3) + j;
      v = (i < 4) ? rpw[(i*128 + o)*128 + c]
        : (i == 4) ? c1w[o*128 + c] : c2w[o*128 + c];
    } else {                             // final frags
      int e2 = e - WF_OFF;
      int ot = e2 >> 11, r = e2 & 2047;
      int kb = r >> 9, r2 = r & 511;
      int l = r2 >> 3, j = r2 & 7;
      int o = ot*16 + (l & 15);
      int c = kb*32 + ((l >> 4) << 3) + j;
      v = fw[o*128 + c];
    }
    wsb[e] = f2bf(v);
  }
}

// ---- directional conv 128->128 via MFMA, tap-outer weight loop ----
// wave owns o-tiles {2og,2og+1} (32 ch) and NTL row-tiles starting at T0
template<int NTL>
__device__ __forceinline__ void dconv_mfma(const u16* __restrict__ As, u16* __restrict__ Bs,
    const u16* __restrict__ wloc, const float* __restrict__ bias,
    int lane, int og, int T0, int off0, int off2)
{
  const int col = lane & 15, kg = lane >> 4, koff = kg*8;
  f32x4 bz0 = *(const f32x4*)(bias + og*32 + kg*4);
  f32x4 bz1 = *(const f32x4*)(bias + og*32 + 16 + kg*4);
  f32x4 acc0[NTL], acc1[NTL];
  #pragma unroll
  for (int t=0;t<NTL;++t){ acc0[t]=bz0; acc1[t]=bz1; }
  const int c1 = (col+1)*ROWP + koff;
  #pragma unroll
  for (int tap=0; tap<3; ++tap){
    const int offr = (tap==0) ? off0 : (tap==1) ? 0 : off2;
    bf16x8 w0[4], w1[4];
    #pragma unroll
    for (int kb=0;kb<4;++kb){
      w0[kb] = *(const bf16x8*)(wloc + (2*og  )*6144 + (tap*4+kb)*512 + lane*8);
      w1[kb] = *(const bf16x8*)(wloc + (2*og+1)*6144 + (tap*4+kb)*512 + lane*8);
    }
    #pragma unroll
    for (int t=0;t<NTL;++t){
      const u16* s = As + (T0+t+1)*RSTRIDE17 + c1 + offr;
      __builtin_amdgcn_s_setprio(1);
      #pragma unroll
      for (int kb=0;kb<4;++kb){
        bf16x8 v = *(const bf16x8*)(s + kb*32);
        acc0[t] = mfma16(w0[kb], v, acc0[t]);
        acc1[t] = mfma16(w1[kb], v, acc1[t]);
      }
      __builtin_amdgcn_s_setprio(0);
    }
  }
  if (col < 15){
    #pragma unroll
    for (int t=0;t<NTL;++t){
      u16* dp = Bs + ((T0+t)*16+col)*ROWP + og*32 + kg*4;
      uint2 v0; v0.x = packbf(silu_f(acc0[t][0]), silu_f(acc0[t][1]));
      v0.y = packbf(silu_f(acc0[t][2]), silu_f(acc0[t][3]));
      *(uint2*)dp = v0;
      uint2 v1; v1.x = packbf(silu_f(acc1[t][0]), silu_f(acc1[t][1]));
      v1.y = packbf(silu_f(acc1[t][2]), silu_f(acc1[t][3]));
      *(uint2*)(dp+16) = v1;
    }
  }
}

// ---- pointwise 128->128 via MFMA; wave owns 4 o-tiles (64 ch), NTL tiles at T0 ----
template<int NTL, bool SRC_HALO, bool DST_HALO, bool RESID>
__device__ __forceinline__ void pw_mfma(const u16* __restrict__ src, u16* __restrict__ dst,
    const u16* __restrict__ wloc, const float* __restrict__ bias,
    int lane, int og2, int T0)
{
  const int col = lane & 15, kg = lane >> 4, koff = kg*8;
  bf16x8 wp[4][4];
  #pragma unroll
  for (int ot=0; ot<4; ++ot)
    #pragma unroll
    for (int kb=0; kb<4; ++kb)
      wp[ot][kb] = *(const bf16x8*)(wloc + (og2*4+ot)*2048 + kb*512 + lane*8);
  f32x4 bz[4];
  #pragma unroll
  for (int ot=0; ot<4; ++ot) bz[ot] = *(const f32x4*)(bias + og2*64 + ot*16 + kg*4);
  const int c1 = (col+1)*ROWP + koff;
  #pragma unroll
  for (int t=0;t<NTL;++t){
    const int tile = T0 + t;
    const int rh = (tile+1)*RSTRIDE17 + c1;
    const int rc = (tile*16+col)*ROWP + koff;
    const u16* S = src + (SRC_HALO ? rh : rc);
    f32x4 a0 = bz[0], a1 = bz[1], a2 = bz[2], a3 = bz[3];
    __builtin_amdgcn_s_setprio(1);
    #pragma unroll
    for (int kb=0; kb<4; ++kb){
      bf16x8 v = *(const bf16x8*)(S + kb*32);
      a0 = mfma16(wp[0][kb], v, a0);
      a1 = mfma16(wp[1][kb], v, a1);
      a2 = mfma16(wp[2][kb], v, a2);
      a3 = mfma16(wp[3][kb], v, a3);
    }
    __builtin_amdgcn_s_setprio(0);
    if (col < 15){
      u16* dp = dst + (DST_HALO ? rh : rc) - koff + og2*64 + kg*4;
      f32x4 aa[4] = {a0, a1, a2, a3};
      #pragma unroll
      for (int ot=0; ot<4; ++ot){
        u16* dq = dp + ot*16;
        float s0 = silu_f(aa[ot][0]), s1 = silu_f(aa[ot][1]);
        float s2 = silu_f(aa[ot][2]), s3 = silu_f(aa[ot][3]);
        if (RESID){
          uint2 r = *(const uint2*)dq;
          s0 += bflo(r.x); s1 += bfhi(r.x); s2 += bflo(r.y); s3 += bfhi(r.y);
        }
        uint2 w0v; w0v.x = packbf(s0, s1); w0v.y = packbf(s2, s3);
        *(uint2*)dq = w0v;
      }
    }
  }
}

// ---- final 1x1 128->64; wave owns 2 o-tiles (32 ch), NTL tiles at T0 ----
template<int NTL>
__device__ __forceinline__ void fin_mfma(const u16* __restrict__ As,
    const u16* __restrict__ wloc, const float* __restrict__ bias,
    float* __restrict__ out, int lane, int ogf, int T0, int bd)
{
  const int col = lane & 15, kg = lane >> 4, koff = kg*8;
  bf16x8 wf[2][4];
  #pragma unroll
  for (int ot=0; ot<2; ++ot)
    #pragma unroll
    for (int kb=0; kb<4; ++kb)
      wf[ot][kb] = *(const bf16x8*)(wloc + (ogf*2+ot)*2048 + kb*512 + lane*8);
  f32x4 bz0 = *(const f32x4*)(bias + ogf*32 + kg*4);
  f32x4 bz1 = *(const f32x4*)(bias + ogf*32 + 16 + kg*4);
  const int c1 = (col+1)*ROWP + koff;
  #pragma unroll
  for (int t=0;t<NTL;++t){
    const int tile = T0 + t;
    const u16* S = As + (tile+1)*RSTRIDE17 + c1;
    f32x4 a0 = bz0, a1 = bz1;
    __builtin_amdgcn_s_setprio(1);
    #pragma unroll
    for (int kb=0; kb<4; ++kb){
      bf16x8 v = *(const bf16x8*)(S + kb*32);
      a0 = mfma16(wf[0][kb], v, a0);
      a1 = mfma16(wf[1][kb], v, a1);
    }
    __builtin_amdgcn_s_setprio(0);
    if (col < 15){
      float* op = out + ((size_t)(bd*64 + ogf*32 + kg*4))*NPOS + tile*15 + col;
      op[0]      = a0[0];
      op[NPOS]   = a0[1];
      op[2*NPOS] = a0[2];
      op[3*NPOS] = a0[3];
      float* oq = op + 16*NPOS;
      oq[0]      = a1[0];
      oq[NPOS]   = a1[1];
      oq[2*NPOS] = a1[2];
      oq[3*NPOS] = a1[3];
    }
  }
}

// 16-wave block, 1 block/CU. Pin waves/EU to exactly 4 -> VGPR budget 512/4 = 128.
__global__ void
__attribute__((amdgpu_flat_work_group_size(1024, 1024), amdgpu_waves_per_eu(4, 4)))
mix9_main(const float* __restrict__ x,
          const float* __restrict__ b_d0,
          const float* __restrict__ b_rd,
          const float* __restrict__ b_rp,
          const float* __restrict__ b_c1,
          const float* __restrict__ b_c2,
          const float* __restrict__ b_fin,
          const float* __restrict__ wt,
          float* __restrict__ out)
{
  extern __shared__ u16 sm[];
  u16* As = sm;              // [289][136] haloed bf16 activations, zero halo
  u16* Bs = sm + A_ELEMS;    // [241][136] compact p'-row scratch

  const int blk  = blockIdx.x;
  const int b    = blk >> 2, d = blk & 3;
  const int tid  = threadIdx.x;
  const int wave = __builtin_amdgcn_readfirstlane(tid >> 6);
  const int lane = tid & 63;

  // dconv split: 4 o-groups (2 o-tiles) x 4 position groups {4,4,4,3} tiles
  const int ogd  = wave >> 2;
  const int pgd  = wave & 3;
  // pw/final split: 2 o-groups x 8 position groups {2,...,2,1} tiles
  const int og2  = wave >> 3;
  const int pg8  = wave & 7;
  // dconv0 prologue split: 8 channel groups x 2 position halves
  const int ob   = (wave & 7) * 16;
  const int phal = wave >> 3;

  const int DI0[4] = {0,-1, 1,-1}, DJ0[4] = {-1, 0,-1,-1};
  const int DI2[4] = {0, 1,-1, 1}, DJ2[4] = { 1, 0, 1, 1};
  const int di0 = DI0[d], dj0 = DJ0[d], di2 = DI2[d], dj2 = DJ2[d];
  const int off0 = (di0*17 + dj0)*ROWP;
  const int off2 = (di2*17 + dj2)*ROWP;

  // zero haloed A; stage input image into B-region as fp32
  for (int k2 = tid; k2 < A_ELEMS; k2 += 1024) As[k2] = 0;
  float* xs = (float*)Bs;          // 450 floats
  for (int k2 = tid; k2 < 2*NPOS; k2 += 1024) xs[k2] = x[b*(2*NPOS) + k2];
  __syncthreads();

  // ---- dconv0: 2 -> 128 (tiny K: plain VALU, fp32 weights) -> A ----
  #pragma unroll 1
  for (int pb = 0; pb < 2; ++pb){
    int pp = phal*128 + pb*64 + lane;   // p' = i*16 + j, covers [0,256)
    int i = pp >> 4, j = pp & 15;
    if (i >= 15 || j >= 15) continue;
    float acc[16];
    #pragma unroll
    for (int oo=0;oo<16;++oo) acc[oo] = b_d0[ob+oo];
    #pragma unroll
    for (int c=0;c<2;++c){
      int i0=i+di0, j0=j+dj0, i2=i+di2, j2=j+dj2;
      float x0 = ((unsigned)i0<15u && (unsigned)j0<15u) ? xs[c*NPOS + i0*15 + j0] : 0.f;
      float x1 = xs[c*NPOS + i*15 + j];
      float x2 = ((unsigned)i2<15u && (unsigned)j2<15u) ? xs[c*NPOS + i2*15 + j2] : 0.f;
      const float* w0r = wt + (c*3+0)*128 + ob;
      const float* w1r = wt + (c*3+1)*128 + ob;
      const float* w2r = wt + (c*3+2)*128 + ob;
      #pragma unroll
      for (int oo=0;oo<16;++oo)
        acc[oo] = fmaf(w0r[oo],x0, fmaf(w1r[oo],x1, fmaf(w2r[oo],x2, acc[oo])));
    }
    u16* dp = As + ((i+1)*17 + (j+1))*ROWP + ob;
    #pragma unroll
    for (int oo=0;oo<16;oo+=2)
      *(u32*)(dp+oo) = packbf(silu_f(acc[oo]), silu_f(acc[oo+1]));
  }
  __syncthreads();

  const u16* wsb = (const u16*)(wt + 768);

  // ---- 4 directional res blocks (MFMA) ----
  #pragma unroll 1
  for (int L = 0; L < 4; ++L){
    if (pgd == 3)
      dconv_mfma<3>(As, Bs, wsb + L*WA_PER_L, b_rd + L*128, lane, ogd, 12, off0, off2);
    else
      dconv_mfma<4>(As, Bs, wsb + L*WA_PER_L, b_rd + L*128, lane, ogd, pgd*4, off0, off2);
    __syncthreads();
    if (pg8 == 7)
      pw_mfma<1,false,true,true>(Bs, As, wsb + WP_OFF + L*WP_PER, b_rp + L*128, lane, og2, 14);
    else
      pw_mfma<2,false,true,true>(Bs, As, wsb + WP_OFF + L*WP_PER, b_rp + L*128, lane, og2, pg8*2);
    __syncthreads();
  }

  // ---- Conv0d res block ----
  if (pg8 == 7)
    pw_mfma<1,true,false,false>(As, Bs, wsb + WP_OFF + 4*WP_PER, b_c1, lane, og2, 14);
  else
    pw_mfma<2,true,false,false>(As, Bs, wsb + WP_OFF + 4*WP_PER, b_c1, lane, og2, pg8*2);
  __syncthreads();
  if (pg8 == 7)
    pw_mfma<1,false,true,true>(Bs, As, wsb + WP_OFF + 5*WP_PER, b_c2, lane, og2, 14);
  else
    pw_mfma<2,false,true,true>(Bs, As, wsb + WP_OFF + 5*WP_PER, b_c2, lane, og2, pg8*2);
  __syncthreads();

  // ---- final 1x1: 128 -> 64, MFMA, write global fp32 ----
  if (pg8 == 7)
    fin_mfma<1>(As, wsb + WF_OFF, b_fin, out, lane, og2, 14, b*4 + d);
  else
    fin_mfma<2>(As, wsb + WF_OFF, b_fin, out, lane, og2, pg8*2, b*4 + d);
}

extern "C" void kernel_launch(void* const* d_in, const int* in_sizes, int n_in,
                              void* d_out, int out_size, void* d_ws, size_t ws_size,
                              hipStream_t stream)
{
  const float* x     = (const float*)d_in[0];
  const float* w_d0  = (const float*)d_in[1];
  const float* b_d0  = (const float*)d_in[2];
  const float* w_rd  = (const float*)d_in[3];
  const float* b_rd  = (const float*)d_in[4];
  const float* w_rp  = (const float*)d_in[5];
  const float* b_rp  = (const float*)d_in[6];
  const float* w_c1  = (const float*)d_in[7];
  const float* b_c1  = (const float*)d_in[8];
  const float* w_c2  = (const float*)d_in[9];
  const float* b_c2  = (const float*)d_in[10];
  const float* w_fin = (const float*)d_in[11];
  const float* b_fin = (const float*)d_in[12];
  float* wt  = (float*)d_ws;
  float* out = (float*)d_out;

  prep_w<<<128, 512, 0, stream>>>(w_d0, w_rd, w_rp, w_c1, w_c2, w_fin, wt);

  (void)hipFuncSetAttribute((const void*)mix9_main,
                            hipFuncAttributeMaxDynamicSharedMemorySize, LDS_BYTES);
  mix9_main<<<1024, 1024, LDS_BYTES, stream>>>(x, b_d0, b_rd, b_rp, b_c1, b_c2, b_fin, wt, out);
}

// Round 9
// 243.994 us; speedup vs baseline: 1.7044x; 1.7044x over previous
//
#include <hip/hip_runtime.h>

using u16 = unsigned short;
using u32 = unsigned int;

typedef __bf16 bf16x8 __attribute__((ext_vector_type(8)));
typedef float  f32x4  __attribute__((ext_vector_type(4)));

#define NPOS   225          // 15*15 valid positions
#define NT     15           // row-tiles; p' = i*16 + j (j<15 valid)
#define ROWP   136          // padded LDS row stride in ushorts (272B, 16B-aligned)
#define A_ROWS 289          // 17*17 haloed
#define B_ROWS 241          // 240 p' rows + 1 guard
#define A_ELEMS (A_ROWS*ROWP)            // 39304 u16
#define B_ELEMS (B_ROWS*ROWP)            // 32776 u16
#define LDS_BYTES ((A_ELEMS + B_ELEMS)*2)  // 144160 B < 160 KiB
#define RSTRIDE17 (17*ROWP)              // 2312

// ---- workspace layout ----
// floats [0..768): dconv0 weights transposed [k=c*3+t][o]
// then bf16 (u16) region, offsets in u16 units:
#define WA_PER_L 49152      // per dconv layer: [8 ot][12 f=t*4+kb][64 lane][8]
#define WP_OFF   (4*WA_PER_L)          // 196608 ; 6 x [8 ot][4 kb][64][8]
#define WP_PER   16384
#define WF_OFF   (WP_OFF + 6*WP_PER)   // 294912 ; [4 ot][4 kb][64][8]
#define W_U16_TOTAL (WF_OFF + 8192)    // 303104

__device__ __forceinline__ float bflo(u32 q){ return __uint_as_float(q << 16); }
__device__ __forceinline__ float bfhi(u32 q){ return __uint_as_float(q & 0xffff0000u); }
__device__ __forceinline__ u16 f2bf(float f){
  u32 u = __float_as_uint(f);
  return (u16)((u + 0x7fffu + ((u >> 16) & 1u)) >> 16);   // RNE (prep kernel only)
}
__device__ __forceinline__ u32 packbf(float a, float b){
  union { __bf16 h[2]; u32 u; } r;
  r.h[0] = (__bf16)a; r.h[1] = (__bf16)b;   // native cast -> v_cvt_pk_bf16_f32
  return r.u;
}
__device__ __forceinline__ float silu_f(float x){
  return x * __builtin_amdgcn_rcpf(1.f + __expf(-x));
}
__device__ __forceinline__ f32x4 mfma16(bf16x8 a, bf16x8 b, f32x4 c){
  return __builtin_amdgcn_mfma_f32_16x16x32_bf16(a, b, c, 0, 0, 0);
}

// ---- weight prep: fp32 transpose for dconv0 + bf16 per-lane fragment swizzle ----
__global__ void prep_w(const float* __restrict__ d0w, const float* __restrict__ rdw,
                       const float* __restrict__ rpw, const float* __restrict__ c1w,
                       const float* __restrict__ c2w, const float* __restrict__ fw,
                       float* __restrict__ ws)
{
  u16* wsb = (u16*)(ws + 768);
  const int total = 768 + W_U16_TOTAL;
  for (int idx = blockIdx.x*blockDim.x + threadIdx.x; idx < total; idx += gridDim.x*blockDim.x){
    if (idx < 768){                      // dconv0 fp32: [6][128] <- [128][2][3]
      int k = idx >> 7, o = idx & 127;
      ws[idx] = d0w[o*6 + k];
      continue;
    }
    int e = idx - 768;
    float v;
    if (e < WP_OFF){                     // res dconv frags
      int L = e / WA_PER_L, r = e % WA_PER_L;
      int w = r / 6144, r2 = r % 6144;
      int t = r2 >> 11, r3 = r2 & 2047;  // t stride 2048
      int kb = r3 >> 9, r4 = r3 & 511;
      int l = r4 >> 3, j = r4 & 7;
      int o = w*16 + (l & 15);
      int c = kb*32 + ((l >> 4) << 3) + j;
      v = rdw[((L*128 + o)*128 + c)*3 + t];
    } else if (e < WF_OFF){              // pointwise frags (res0..3, c1, c2)
      int t2 = e - WP_OFF;
      int i = t2 / WP_PER, r = t2 % WP_PER;
      int w = r >> 11, r2 = r & 2047;
      int kb = r2 >> 9, r3 = r2 & 511;
      int l = r3 >> 3, j = r3 & 7;
      int o = w*16 + (l & 15);
      int c = kb*32 + ((l >> 4) << 3) + j;
      v = (i < 4) ? rpw[(i*128 + o)*128 + c]
        : (i == 4) ? c1w[o*128 + c] : c2w[o*128 + c];
    } else {                             // final frags
      int e2 = e - WF_OFF;
      int ot = e2 >> 11, r = e2 & 2047;
      int kb = r >> 9, r2 = r & 511;
      int l = r2 >> 3, j = r2 & 7;
      int o = ot*16 + (l & 15);
      int c = kb*32 + ((l >> 4) << 3) + j;
      v = fw[o*128 + c];
    }
    wsb[e] = f2bf(v);
  }
}

// ---- directional conv 128->128 via MFMA: A(haloed) -> B(compact p' rows) ----
// wave owns o-tiles {2og, 2og+1} (32 ch), all weights resident, tiles [T0,T1)
__device__ __forceinline__ void dconv_mfma(const u16* __restrict__ As, u16* __restrict__ Bs,
    const u16* __restrict__ wloc, const float* __restrict__ bias,
    int lane, int og, int T0, int T1, int off0, int off2)
{
  const int col = lane & 15, kg = lane >> 4, koff = kg*8;
  bf16x8 wa[2][12];
  #pragma unroll
  for (int ot=0; ot<2; ++ot)
    #pragma unroll
    for (int f=0; f<12; ++f)
      wa[ot][f] = *(const bf16x8*)(wloc + (2*og+ot)*6144 + f*512 + lane*8);
  f32x4 bz0 = *(const f32x4*)(bias + og*32 + kg*4);
  f32x4 bz1 = *(const f32x4*)(bias + og*32 + 16 + kg*4);
  const int c1 = (col+1)*ROWP;
  #pragma unroll 1
  for (int tile=T0; tile<T1; ++tile){
    int rb = (tile+1)*RSTRIDE17 + c1;
    const u16* s0 = As + rb + off0 + koff;
    const u16* s1 = As + rb + koff;
    const u16* s2 = As + rb + off2 + koff;
    f32x4 a0 = bz0, a1 = bz1;
    __builtin_amdgcn_s_setprio(1);
    #pragma unroll
    for (int kb=0; kb<4; ++kb){
      bf16x8 v0 = *(const bf16x8*)(s0 + kb*32);
      bf16x8 v1 = *(const bf16x8*)(s1 + kb*32);
      bf16x8 v2 = *(const bf16x8*)(s2 + kb*32);
      a0 = mfma16(wa[0][kb],   v0, a0); a1 = mfma16(wa[1][kb],   v0, a1);
      a0 = mfma16(wa[0][4+kb], v1, a0); a1 = mfma16(wa[1][4+kb], v1, a1);
      a0 = mfma16(wa[0][8+kb], v2, a0); a1 = mfma16(wa[1][8+kb], v2, a1);
    }
    __builtin_amdgcn_s_setprio(0);
    if (col < 15){
      u16* dp = Bs + (tile*16+col)*ROWP + og*32 + kg*4;
      uint2 w0; w0.x = packbf(silu_f(a0[0]), silu_f(a0[1]));
      w0.y = packbf(silu_f(a0[2]), silu_f(a0[3]));
      *(uint2*)dp = w0;
      uint2 w1; w1.x = packbf(silu_f(a1[0]), silu_f(a1[1]));
      w1.y = packbf(silu_f(a1[2]), silu_f(a1[3]));
      *(uint2*)(dp+16) = w1;
    }
  }
}

// ---- pointwise 128->128 via MFMA; wave owns 4 o-tiles (64 ch), tiles [T0,T1) ----
template<bool SRC_HALO, bool DST_HALO, bool RESID>
__device__ __forceinline__ void pw_mfma(const u16* __restrict__ src, u16* __restrict__ dst,
    const u16* __restrict__ wloc, const float* __restrict__ bias,
    int lane, int og2, int T0, int T1)
{
  const int col = lane & 15, kg = lane >> 4, koff = kg*8;
  bf16x8 wp[4][4];
  #pragma unroll
  for (int ot=0; ot<4; ++ot)
    #pragma unroll
    for (int kb=0; kb<4; ++kb)
      wp[ot][kb] = *(const bf16x8*)(wloc + (og2*4+ot)*2048 + kb*512 + lane*8);
  f32x4 bz[4];
  #pragma unroll
  for (int ot=0; ot<4; ++ot) bz[ot] = *(const f32x4*)(bias + og2*64 + ot*16 + kg*4);
  const int chb = og2*64 + kg*4;
  const int c1 = (col+1)*ROWP;
  #pragma unroll 2
  for (int tile=T0; tile<T1; ++tile){
    const int rh = (tile+1)*RSTRIDE17 + c1;
    const int rc = (tile*16+col)*ROWP;
    const u16* S = src + (SRC_HALO ? rh : rc) + koff;
    f32x4 a0 = bz[0], a1 = bz[1], a2 = bz[2], a3 = bz[3];
    __builtin_amdgcn_s_setprio(1);
    #pragma unroll
    for (int kb=0; kb<4; ++kb){
      bf16x8 v = *(const bf16x8*)(S + kb*32);
      a0 = mfma16(wp[0][kb], v, a0);
      a1 = mfma16(wp[1][kb], v, a1);
      a2 = mfma16(wp[2][kb], v, a2);
      a3 = mfma16(wp[3][kb], v, a3);
    }
    __builtin_amdgcn_s_setprio(0);
    if (col < 15){
      u16* dp = dst + (DST_HALO ? rh : rc) + chb;
      f32x4 aa[4] = {a0, a1, a2, a3};
      #pragma unroll
      for (int ot=0; ot<4; ++ot){
        u16* dq = dp + ot*16;
        float s0 = silu_f(aa[ot][0]), s1 = silu_f(aa[ot][1]);
        float s2 = silu_f(aa[ot][2]), s3 = silu_f(aa[ot][3]);
        if (RESID){
          uint2 r = *(const uint2*)dq;
          s0 += bflo(r.x); s1 += bfhi(r.x); s2 += bflo(r.y); s3 += bfhi(r.y);
        }
        uint2 w0v; w0v.x = packbf(s0, s1); w0v.y = packbf(s2, s3);
        *(uint2*)dq = w0v;
      }
    }
  }
}

// ---- final 1x1 128->64; wave owns 2 o-tiles (32 ch), tiles [T0,T1) ----
__device__ __forceinline__ void fin_mfma(const u16* __restrict__ As,
    const u16* __restrict__ wloc, const float* __restrict__ bias,
    float* __restrict__ out, int lane, int ogf, int T0, int T1, int bd)
{
  const int col = lane & 15, kg = lane >> 4, koff = kg*8;
  bf16x8 wf[2][4];
  #pragma unroll
  for (int ot=0; ot<2; ++ot)
    #pragma unroll
    for (int kb=0; kb<4; ++kb)
      wf[ot][kb] = *(const bf16x8*)(wloc + (ogf*2+ot)*2048 + kb*512 + lane*8);
  f32x4 bz0 = *(const f32x4*)(bias + ogf*32 + kg*4);
  f32x4 bz1 = *(const f32x4*)(bias + ogf*32 + 16 + kg*4);
  const int c1 = (col+1)*ROWP;
  #pragma unroll 1
  for (int tile=T0; tile<T1; ++tile){
    const u16* S = As + (tile+1)*RSTRIDE17 + c1 + koff;
    f32x4 a0 = bz0, a1 = bz1;
    __builtin_amdgcn_s_setprio(1);
    #pragma unroll
    for (int kb=0; kb<4; ++kb){
      bf16x8 v = *(const bf16x8*)(S + kb*32);
      a0 = mfma16(wf[0][kb], v, a0);
      a1 = mfma16(wf[1][kb], v, a1);
    }
    __builtin_amdgcn_s_setprio(0);
    if (col < 15){
      float* op = out + ((size_t)(bd*64 + ogf*32 + kg*4))*NPOS + tile*15 + col;
      op[0]      = a0[0];
      op[NPOS]   = a0[1];
      op[2*NPOS] = a0[2];
      op[3*NPOS] = a0[3];
      float* oq = op + 16*NPOS;
      oq[0]      = a1[0];
      oq[NPOS]   = a1[1];
      oq[2*NPOS] = a1[2];
      oq[3*NPOS] = a1[3];
    }
  }
}

__global__ void __launch_bounds__(512, 2)
mix9_main(const float* __restrict__ x,
          const float* __restrict__ b_d0,
          const float* __restrict__ b_rd,
          const float* __restrict__ b_rp,
          const float* __restrict__ b_c1,
          const float* __restrict__ b_c2,
          const float* __restrict__ b_fin,
          const float* __restrict__ wt,
          float* __restrict__ out)
{
  extern __shared__ u16 sm[];
  u16* As = sm;              // [289][136] haloed bf16 activations, zero halo
  u16* Bs = sm + A_ELEMS;    // [241][136] compact p'-row scratch

  const int blk  = blockIdx.x;
  const int b    = blk >> 2, d = blk & 3;
  const int tid  = threadIdx.x;
  const int wave = __builtin_amdgcn_readfirstlane(tid >> 6);
  const int lane = tid & 63;

  // dconv split: 4 o-groups (2 o-tiles each) x 2 position halves
  const int ogd  = wave >> 1;
  const int phd  = wave & 1;
  const int T0d  = phd * 8;
  const int T1d  = phd ? NT : 8;
  // pw/final split: 2 o-groups x 4 position quarters
  const int og2  = wave >> 2;
  const int ph4  = wave & 3;
  const int T0p  = ph4 * 4;
  const int T1p  = (ph4 == 3) ? NT : T0p + 4;
  // dconv0 prologue channel base
  const int ob   = wave * 16;

  const int DI0[4] = {0,-1, 1,-1}, DJ0[4] = {-1, 0,-1,-1};
  const int DI2[4] = {0, 1,-1, 1}, DJ2[4] = { 1, 0, 1, 1};
  const int di0 = DI0[d], dj0 = DJ0[d], di2 = DI2[d], dj2 = DJ2[d];
  const int off0 = (di0*17 + dj0)*ROWP;
  const int off2 = (di2*17 + dj2)*ROWP;

  // zero haloed A; stage input image into B-region as fp32
  for (int k2 = tid; k2 < A_ELEMS; k2 += 512) As[k2] = 0;
  float* xs = (float*)Bs;          // 450 floats
  for (int k2 = tid; k2 < 2*NPOS; k2 += 512) xs[k2] = x[b*(2*NPOS) + k2];
  __syncthreads();

  // ---- dconv0: 2 -> 128 (tiny K: plain VALU, fp32 weights) -> A ----
  #pragma unroll 1
  for (int pb = 0; pb < 4; ++pb){
    int pp = pb*64 + lane;           // p' = i*16 + j
    int i = pp >> 4, j = pp & 15;
    if (i >= 15 || j >= 15) continue;
    float acc[16];
    #pragma unroll
    for (int oo=0;oo<16;++oo) acc[oo] = b_d0[ob+oo];
    #pragma unroll
    for (int c=0;c<2;++c){
      int i0=i+di0, j0=j+dj0, i2=i+di2, j2=j+dj2;
      float x0 = ((unsigned)i0<15u && (unsigned)j0<15u) ? xs[c*NPOS + i0*15 + j0] : 0.f;
      float x1 = xs[c*NPOS + i*15 + j];
      float x2 = ((unsigned)i2<15u && (unsigned)j2<15u) ? xs[c*NPOS + i2*15 + j2] : 0.f;
      const float* w0r = wt + (c*3+0)*128 + ob;
      const float* w1r = wt + (c*3+1)*128 + ob;
      const float* w2r = wt + (c*3+2)*128 + ob;
      #pragma unroll
      for (int oo=0;oo<16;++oo)
        acc[oo] = fmaf(w0r[oo],x0, fmaf(w1r[oo],x1, fmaf(w2r[oo],x2, acc[oo])));
    }
    u16* dp = As + ((i+1)*17 + (j+1))*ROWP + ob;
    #pragma unroll
    for (int oo=0;oo<16;oo+=2)
      *(u32*)(dp+oo) = packbf(silu_f(acc[oo]), silu_f(acc[oo+1]));
  }
  __syncthreads();

  const u16* wsb = (const u16*)(wt + 768);

  // ---- 4 directional res blocks (MFMA) ----
  #pragma unroll 1
  for (int L = 0; L < 4; ++L){
    dconv_mfma(As, Bs, wsb + L*WA_PER_L, b_rd + L*128, lane, ogd, T0d, T1d, off0, off2);
    __syncthreads();
    pw_mfma<false,true,true>(Bs, As, wsb + WP_OFF + L*WP_PER, b_rp + L*128, lane, og2, T0p, T1p);
    __syncthreads();
  }

  // ---- Conv0d res block ----
  pw_mfma<true,false,false>(As, Bs, wsb + WP_OFF + 4*WP_PER, b_c1, lane, og2, T0p, T1p);
  __syncthreads();
  pw_mfma<false,true,true>(Bs, As, wsb + WP_OFF + 5*WP_PER, b_c2, lane, og2, T0p, T1p);
  __syncthreads();

  // ---- final 1x1: 128 -> 64, MFMA, write global fp32 ----
  fin_mfma(As, wsb + WF_OFF, b_fin, out, lane, og2, T0p, T1p, b*4 + d);
}

extern "C" void kernel_launch(void* const* d_in, const int* in_sizes, int n_in,
                              void* d_out, int out_size, void* d_ws, size_t ws_size,
                              hipStream_t stream)
{
  const float* x     = (const float*)d_in[0];
  const float* w_d0  = (const float*)d_in[1];
  const float* b_d0  = (const float*)d_in[2];
  const float* w_rd  = (const float*)d_in[3];
  const float* b_rd  = (const float*)d_in[4];
  const float* w_rp  = (const float*)d_in[5];
  const float* b_rp  = (const float*)d_in[6];
  const float* w_c1  = (const float*)d_in[7];
  const float* b_c1  = (const float*)d_in[8];
  const float* w_c2  = (const float*)d_in[9];
  const float* b_c2  = (const float*)d_in[10];
  const float* w_fin = (const float*)d_in[11];
  const float* b_fin = (const float*)d_in[12];
  float* wt  = (float*)d_ws;
  float* out = (float*)d_out;

  prep_w<<<128, 512, 0, stream>>>(w_d0, w_rd, w_rp, w_c1, w_c2, w_fin, wt);

  (void)hipFuncSetAttribute((const void*)mix9_main,
                            hipFuncAttributeMaxDynamicSharedMemorySize, LDS_BYTES);
  mix9_main<<<1024, 512, LDS_BYTES, stream>>>(x, b_d0, b_rd, b_rp, b_c1, b_c2, b_fin, wt, out);
}

// Round 10
// 243.461 us; speedup vs baseline: 1.7081x; 1.0022x over previous
//
#include <hip/hip_runtime.h>

using u16 = unsigned short;
using u32 = unsigned int;

typedef __bf16 bf16x8 __attribute__((ext_vector_type(8)));
typedef float  f32x4  __attribute__((ext_vector_type(4)));

#define NPOS   225          // 15*15 valid positions
#define NT     15           // row-tiles; p' = i*16 + j (j<15 valid)
#define ROWP   136          // padded LDS row stride in ushorts (272B; 68 dw, odd*4 -> uniform banks)
#define A_ROWS 289          // 17*17 haloed
#define B_ROWS 241          // 240 p' rows + 1 guard
#define A_ELEMS (A_ROWS*ROWP)            // 39304 u16
#define B_ELEMS (B_ROWS*ROWP)            // 32776 u16
#define LDS_BYTES ((A_ELEMS + B_ELEMS)*2)  // 144160 B < 160 KiB
#define RSTRIDE17 (17*ROWP)              // 2312

// ---- workspace layout ----
// floats [0..768): dconv0 weights [k=c*3+t][s_o] (o-dim stored-order, perm'd)
// floats [768..896): dconv0 bias, perm'd
// then bf16 (u16) region, offsets in u16 units:
#define WA_PER_L 49152      // per dconv layer: [og 2][tap 3][ot 4][kb 4][lane 64][8]
#define WP_OFF   (4*WA_PER_L)          // 196608 ; 6 x [og2 2][ot 4][kb 4][64][8]
#define WP_PER   16384
#define WF_OFF   (WP_OFF + 6*WP_PER)   // 294912 ; [4 ot][4 kb][64][8]
#define W_U16_TOTAL (WF_OFF + 8192)    // 303104

// storage<->logical channel permutation: swap bits[5:4] and [3:2]; self-inverse
__host__ __device__ __forceinline__ int permc(int c){
  return (c & ~0x3C) | (((c >> 2) & 3) << 4) | (((c >> 4) & 3) << 2);
}

__device__ __forceinline__ float bflo(u32 q){ return __uint_as_float(q << 16); }
__device__ __forceinline__ float bfhi(u32 q){ return __uint_as_float(q & 0xffff0000u); }
__device__ __forceinline__ u16 f2bf(float f){
  u32 u = __float_as_uint(f);
  return (u16)((u + 0x7fffu + ((u >> 16) & 1u)) >> 16);   // RNE (prep kernel only)
}
__device__ __forceinline__ u32 packbf(float a, float b){
  union { __bf16 h[2]; u32 u; } r;
  r.h[0] = (__bf16)a; r.h[1] = (__bf16)b;   // native cast -> v_cvt_pk_bf16_f32
  return r.u;
}
__device__ __forceinline__ float silu_f(float x){
  return x * __builtin_amdgcn_rcpf(1.f + __expf(-x));
}
__device__ __forceinline__ f32x4 mfma16(bf16x8 a, bf16x8 b, f32x4 c){
  return __builtin_amdgcn_mfma_f32_16x16x32_bf16(a, b, c, 0, 0, 0);
}

// ---- weight prep: perm'd transposes; all k-dims use permc so kernel addressing is linear ----
__global__ void prep_w(const float* __restrict__ d0w, const float* __restrict__ d0b,
                       const float* __restrict__ rdw,
                       const float* __restrict__ rpw, const float* __restrict__ c1w,
                       const float* __restrict__ c2w, const float* __restrict__ fw,
                       float* __restrict__ ws)
{
  u16* wsb = (u16*)(ws + 896);
  const int total = 896 + W_U16_TOTAL;
  for (int idx = blockIdx.x*blockDim.x + threadIdx.x; idx < total; idx += gridDim.x*blockDim.x){
    if (idx < 768){                      // dconv0: ws[k*128+s] = w[perm(s)][k]
      int k = idx >> 7, s = idx & 127;
      ws[idx] = d0w[permc(s)*6 + k];
      continue;
    }
    if (idx < 896){                      // dconv0 bias perm'd
      int s = idx - 768;
      ws[idx] = d0b[permc(s)];
      continue;
    }
    int e = idx - 896;
    float v;
    if (e < WP_OFF){                     // res dconv frags [og][tap][ot][kb][lane][8]
      int L = e / WA_PER_L, r = e % WA_PER_L;
      int og = r / 24576; int r1 = r - og*24576;
      int tap = r1 >> 13; int r2 = r1 & 8191;
      int ot = r2 >> 11, kb = (r2 >> 9) & 3, l = (r2 >> 3) & 63, j = r2 & 7;
      int o = (og*4 + ot)*16 + (l & 15);
      int ks = kb*32 + ((l >> 4) << 3) + j;
      v = rdw[((L*128 + o)*128 + permc(ks))*3 + tap];
    } else if (e < WF_OFF){              // pointwise frags [og2][ot][kb][lane][8]
      int t2 = e - WP_OFF;
      int i = t2 / WP_PER, r = t2 % WP_PER;
      int og2 = r >> 13;
      int ot = (r >> 11) & 3, kb = (r >> 9) & 3, l = (r >> 3) & 63, j = r & 7;
      int o = (og2*4 + ot)*16 + (l & 15);
      int ks = kb*32 + ((l >> 4) << 3) + j;
      v = (i < 4) ? rpw[(i*128 + o)*128 + permc(ks)]
        : (i == 4) ? c1w[o*128 + permc(ks)] : c2w[o*128 + permc(ks)];
    } else {                             // final frags [ot][kb][lane][8]
      int e2 = e - WF_OFF;
      int ot = e2 >> 11, kb = (e2 >> 9) & 3, l = (e2 >> 3) & 63, j = e2 & 7;
      int o = ot*16 + (l & 15);
      int ks = kb*32 + ((l >> 4) << 3) + j;
      v = fw[o*128 + permc(ks)];
    }
    wsb[e] = f2bf(v);
  }
}

// pack 2 accs (8 ch, stored-contiguous) into one uint4 after silu
__device__ __forceinline__ uint4 pack_silu2(const f32x4& a, const f32x4& b){
  uint4 q;
  q.x = packbf(silu_f(a[0]), silu_f(a[1]));
  q.y = packbf(silu_f(a[2]), silu_f(a[3]));
  q.z = packbf(silu_f(b[0]), silu_f(b[1]));
  q.w = packbf(silu_f(b[2]), silu_f(b[3]));
  return q;
}

// ---- directional conv 128->128 via MFMA, tap-outer, 4 o-tiles/wave ----
// wave owns o-tiles [4og,4og+4) (64 ch) and NTL row-tiles starting at T0
template<int NTL>
__device__ __forceinline__ void dconv_mfma(const u16* __restrict__ As, u16* __restrict__ Bs,
    const u16* __restrict__ wloc, const float* __restrict__ bias,
    int lane, int og, int T0, int off0, int off2)
{
  const int col = lane & 15, kg = lane >> 4, koff = kg*8;
  f32x4 acc[4][NTL];
  #pragma unroll
  for (int ot=0; ot<4; ++ot){
    f32x4 bz = *(const f32x4*)(bias + og*64 + ot*16 + kg*4);
    #pragma unroll
    for (int t=0;t<NTL;++t) acc[ot][t] = bz;
  }
  const int c1 = (col+1)*ROWP + koff;
  #pragma unroll 1
  for (int tap=0; tap<3; ++tap){
    const int offr = (tap==0) ? off0 : (tap==1) ? 0 : off2;
    bf16x8 w[4][4];
    #pragma unroll
    for (int ot=0; ot<4; ++ot)
      #pragma unroll
      for (int kb=0; kb<4; ++kb)
        w[ot][kb] = *(const bf16x8*)(wloc + tap*8192 + ot*2048 + kb*512 + lane*8);
    #pragma unroll
    for (int t=0; t<NTL; ++t){
      const u16* s = As + (T0+t+1)*RSTRIDE17 + c1 + offr;
      __builtin_amdgcn_s_setprio(1);
      #pragma unroll
      for (int kb=0; kb<4; ++kb){
        bf16x8 v = *(const bf16x8*)(s + kb*32);
        acc[0][t] = mfma16(w[0][kb], v, acc[0][t]);
        acc[1][t] = mfma16(w[1][kb], v, acc[1][t]);
        acc[2][t] = mfma16(w[2][kb], v, acc[2][t]);
        acc[3][t] = mfma16(w[3][kb], v, acc[3][t]);
      }
      __builtin_amdgcn_s_setprio(0);
    }
  }
  if (col < 15){
    #pragma unroll
    for (int t=0;t<NTL;++t){
      // stored layout: s = og*64 + kg*16 + ot*4 + r -> lane's 16 ch contiguous (32B)
      u16* dp = Bs + ((T0+t)*16+col)*ROWP + og*64 + kg*16;
      uint4 q0 = pack_silu2(acc[0][t], acc[1][t]);
      uint4 q1 = pack_silu2(acc[2][t], acc[3][t]);
      *(uint4*)dp = q0;
      *(uint4*)(dp+8) = q1;
    }
  }
}

// ---- pointwise 128->128 via MFMA; wave owns 4 o-tiles (64 ch), tiles [T0,T1) ----
template<bool SRC_HALO, bool DST_HALO, bool RESID>
__device__ __forceinline__ void pw_mfma(const u16* __restrict__ src, u16* __restrict__ dst,
    const u16* __restrict__ wloc, const float* __restrict__ bias,
    int lane, int og2, int T0, int T1)
{
  const int col = lane & 15, kg = lane >> 4, koff = kg*8;
  bf16x8 wp[4][4];
  #pragma unroll
  for (int ot=0; ot<4; ++ot)
    #pragma unroll
    for (int kb=0; kb<4; ++kb)
      wp[ot][kb] = *(const bf16x8*)(wloc + og2*8192 + ot*2048 + kb*512 + lane*8);
  f32x4 bz[4];
  #pragma unroll
  for (int ot=0; ot<4; ++ot) bz[ot] = *(const f32x4*)(bias + og2*64 + ot*16 + kg*4);
  const int c1 = (col+1)*ROWP;
  #pragma unroll 2
  for (int tile=T0; tile<T1; ++tile){
    const int rh = (tile+1)*RSTRIDE17 + c1;
    const int rc = (tile*16+col)*ROWP;
    const u16* S = src + (SRC_HALO ? rh : rc) + koff;
    f32x4 a0 = bz[0], a1 = bz[1], a2 = bz[2], a3 = bz[3];
    __builtin_amdgcn_s_setprio(1);
    #pragma unroll
    for (int kb=0; kb<4; ++kb){
      bf16x8 v = *(const bf16x8*)(S + kb*32);
      a0 = mfma16(wp[0][kb], v, a0);
      a1 = mfma16(wp[1][kb], v, a1);
      a2 = mfma16(wp[2][kb], v, a2);
      a3 = mfma16(wp[3][kb], v, a3);
    }
    __builtin_amdgcn_s_setprio(0);
    if (col < 15){
      u16* dp = dst + (DST_HALO ? rh : rc) + og2*64 + kg*16;
      float s0 = silu_f(a0[0]), s1 = silu_f(a0[1]), s2 = silu_f(a0[2]), s3 = silu_f(a0[3]);
      float s4 = silu_f(a1[0]), s5 = silu_f(a1[1]), s6 = silu_f(a1[2]), s7 = silu_f(a1[3]);
      float s8 = silu_f(a2[0]), s9 = silu_f(a2[1]), sa = silu_f(a2[2]), sb = silu_f(a2[3]);
      float sc = silu_f(a3[0]), sd = silu_f(a3[1]), se = silu_f(a3[2]), sf = silu_f(a3[3]);
      if (RESID){
        uint4 r0 = *(const uint4*)dp;
        uint4 r1 = *(const uint4*)(dp+8);
        s0 += bflo(r0.x); s1 += bfhi(r0.x); s2 += bflo(r0.y); s3 += bfhi(r0.y);
        s4 += bflo(r0.z); s5 += bfhi(r0.z); s6 += bflo(r0.w); s7 += bfhi(r0.w);
        s8 += bflo(r1.x); s9 += bfhi(r1.x); sa += bflo(r1.y); sb += bfhi(r1.y);
        sc += bflo(r1.z); sd += bfhi(r1.z); se += bflo(r1.w); sf += bfhi(r1.w);
      }
      uint4 q0, q1;
      q0.x = packbf(s0, s1); q0.y = packbf(s2, s3);
      q0.z = packbf(s4, s5); q0.w = packbf(s6, s7);
      q1.x = packbf(s8, s9); q1.y = packbf(sa, sb);
      q1.z = packbf(sc, sd); q1.w = packbf(se, sf);
      *(uint4*)dp = q0;
      *(uint4*)(dp+8) = q1;
    }
  }
}

// ---- final 1x1 128->64; wave owns 2 o-tiles (32 ch), tiles [T0,T1) ----
__device__ __forceinline__ void fin_mfma(const u16* __restrict__ As,
    const u16* __restrict__ wloc, const float* __restrict__ bias,
    float* __restrict__ out, int lane, int ogf, int T0, int T1, int bd)
{
  const int col = lane & 15, kg = lane >> 4, koff = kg*8;
  bf16x8 wf[2][4];
  #pragma unroll
  for (int ot=0; ot<2; ++ot)
    #pragma unroll
    for (int kb=0; kb<4; ++kb)
      wf[ot][kb] = *(const bf16x8*)(wloc + (ogf*2+ot)*2048 + kb*512 + lane*8);
  f32x4 bz0 = *(const f32x4*)(bias + ogf*32 + kg*4);
  f32x4 bz1 = *(const f32x4*)(bias + ogf*32 + 16 + kg*4);
  const int c1 = (col+1)*ROWP;
  #pragma unroll 1
  for (int tile=T0; tile<T1; ++tile){
    const u16* S = As + (tile+1)*RSTRIDE17 + c1 + koff;
    f32x4 a0 = bz0, a1 = bz1;
    __builtin_amdgcn_s_setprio(1);
    #pragma unroll
    for (int kb=0; kb<4; ++kb){
      bf16x8 v = *(const bf16x8*)(S + kb*32);
      a0 = mfma16(wf[0][kb], v, a0);
      a1 = mfma16(wf[1][kb], v, a1);
    }
    __builtin_amdgcn_s_setprio(0);
    if (col < 15){
      float* op = out + ((size_t)(bd*64 + ogf*32 + kg*4))*NPOS + tile*15 + col;
      op[0]      = a0[0];
      op[NPOS]   = a0[1];
      op[2*NPOS] = a0[2];
      op[3*NPOS] = a0[3];
      float* oq = op + 16*NPOS;
      oq[0]      = a1[0];
      oq[NPOS]   = a1[1];
      oq[2*NPOS] = a1[2];
      oq[3*NPOS] = a1[3];
    }
  }
}

__global__ void __launch_bounds__(512, 2)
mix9_main(const float* __restrict__ x,
          const float* __restrict__ b_rd,
          const float* __restrict__ b_rp,
          const float* __restrict__ b_c1,
          const float* __restrict__ b_c2,
          const float* __restrict__ b_fin,
          const float* __restrict__ wt,
          float* __restrict__ out)
{
  extern __shared__ u16 sm[];
  u16* As = sm;              // [289][136] haloed bf16 activations (stored-perm'd ch), zero halo
  u16* Bs = sm + A_ELEMS;    // [241][136] compact p'-row scratch (stored-perm'd ch)

  const int blk  = blockIdx.x;
  const int b    = blk >> 2, d = blk & 3;
  const int tid  = threadIdx.x;
  const int wave = __builtin_amdgcn_readfirstlane(tid >> 6);
  const int lane = tid & 63;

  // dconv split: 2 o-groups (4 o-tiles each) x 4 position groups {4,4,4,3}
  const int ogd  = wave >> 2;
  const int pgd  = wave & 3;
  // pw/final split: 2 o-groups x 4 position quarters
  const int og2  = wave >> 2;
  const int ph4  = wave & 3;
  const int T0p  = ph4 * 4;
  const int T1p  = (ph4 == 3) ? NT : T0p + 4;
  // dconv0 prologue channel base (stored-order; weights/bias perm'd in prep)
  const int ob   = wave * 16;

  const int DI0[4] = {0,-1, 1,-1}, DJ0[4] = {-1, 0,-1,-1};
  const int DI2[4] = {0, 1,-1, 1}, DJ2[4] = { 1, 0, 1, 1};
  const int di0 = DI0[d], dj0 = DJ0[d], di2 = DI2[d], dj2 = DJ2[d];
  const int off0 = (di0*17 + dj0)*ROWP;
  const int off2 = (di2*17 + dj2)*ROWP;

  // zero haloed A; stage input image into B-region as fp32
  for (int k2 = tid; k2 < A_ELEMS; k2 += 512) As[k2] = 0;
  float* xs = (float*)Bs;          // 450 floats
  for (int k2 = tid; k2 < 2*NPOS; k2 += 512) xs[k2] = x[b*(2*NPOS) + k2];
  __syncthreads();

  // ---- dconv0: 2 -> 128 (tiny K: plain VALU, fp32 weights, stored-order o) -> A ----
  const float* b0p = wt + 768;
  #pragma unroll 1
  for (int pb = 0; pb < 4; ++pb){
    int pp = pb*64 + lane;           // p' = i*16 + j
    int i = pp >> 4, j = pp & 15;
    if (i >= 15 || j >= 15) continue;
    float acc[16];
    #pragma unroll
    for (int oo=0;oo<16;++oo) acc[oo] = b0p[ob+oo];
    #pragma unroll
    for (int c=0;c<2;++c){
      int i0=i+di0, j0=j+dj0, i2=i+di2, j2=j+dj2;
      float x0 = ((unsigned)i0<15u && (unsigned)j0<15u) ? xs[c*NPOS + i0*15 + j0] : 0.f;
      float x1 = xs[c*NPOS + i*15 + j];
      float x2 = ((unsigned)i2<15u && (unsigned)j2<15u) ? xs[c*NPOS + i2*15 + j2] : 0.f;
      const float* w0r = wt + (c*3+0)*128 + ob;
      const float* w1r = wt + (c*3+1)*128 + ob;
      const float* w2r = wt + (c*3+2)*128 + ob;
      #pragma unroll
      for (int oo=0;oo<16;++oo)
        acc[oo] = fmaf(w0r[oo],x0, fmaf(w1r[oo],x1, fmaf(w2r[oo],x2, acc[oo])));
    }
    u16* dp = As + ((i+1)*17 + (j+1))*ROWP + ob;
    #pragma unroll
    for (int oo=0;oo<16;oo+=2)
      *(u32*)(dp+oo) = packbf(silu_f(acc[oo]), silu_f(acc[oo+1]));
  }
  __syncthreads();

  const u16* wsb = (const u16*)(wt + 896);

  // ---- 4 directional res blocks (MFMA) ----
  #pragma unroll 1
  for (int L = 0; L < 4; ++L){
    if (pgd == 3)
      dconv_mfma<3>(As, Bs, wsb + L*WA_PER_L + ogd*24576, b_rd + L*128, lane, ogd, 12, off0, off2);
    else
      dconv_mfma<4>(As, Bs, wsb + L*WA_PER_L + ogd*24576, b_rd + L*128, lane, ogd, pgd*4, off0, off2);
    __syncthreads();
    pw_mfma<false,true,true>(Bs, As, wsb + WP_OFF + L*WP_PER, b_rp + L*128, lane, og2, T0p, T1p);
    __syncthreads();
  }

  // ---- Conv0d res block ----
  pw_mfma<true,false,false>(As, Bs, wsb + WP_OFF + 4*WP_PER, b_c1, lane, og2, T0p, T1p);
  __syncthreads();
  pw_mfma<false,true,true>(Bs, As, wsb + WP_OFF + 5*WP_PER, b_c2, lane, og2, T0p, T1p);
  __syncthreads();

  // ---- final 1x1: 128 -> 64, MFMA, write global fp32 ----
  fin_mfma(As, wsb + WF_OFF, b_fin, out, lane, og2, T0p, T1p, b*4 + d);
}

extern "C" void kernel_launch(void* const* d_in, const int* in_sizes, int n_in,
                              void* d_out, int out_size, void* d_ws, size_t ws_size,
                              hipStream_t stream)
{
  const float* x     = (const float*)d_in[0];
  const float* w_d0  = (const float*)d_in[1];
  const float* b_d0  = (const float*)d_in[2];
  const float* w_rd  = (const float*)d_in[3];
  const float* b_rd  = (const float*)d_in[4];
  const float* w_rp  = (const float*)d_in[5];
  const float* b_rp  = (const float*)d_in[6];
  const float* w_c1  = (const float*)d_in[7];
  const float* b_c1  = (const float*)d_in[8];
  const float* w_c2  = (const float*)d_in[9];
  const float* b_c2  = (const float*)d_in[10];
  const float* w_fin = (const float*)d_in[11];
  const float* b_fin = (const float*)d_in[12];
  float* wt  = (float*)d_ws;
  float* out = (float*)d_out;

  prep_w<<<128, 512, 0, stream>>>(w_d0, b_d0, w_rd, w_rp, w_c1, w_c2, w_fin, wt);

  (void)hipFuncSetAttribute((const void*)mix9_main,
                            hipFuncAttributeMaxDynamicSharedMemorySize, LDS_BYTES);
  mix9_main<<<1024, 512, LDS_BYTES, stream>>>(x, b_rd, b_rp, b_c1, b_c2, b_fin, wt, out);
}

// Round 11
// 239.444 us; speedup vs baseline: 1.7367x; 1.0168x over previous
//
#include <hip/hip_runtime.h>

using u16 = unsigned short;
using u32 = unsigned int;

typedef __bf16 bf16x8 __attribute__((ext_vector_type(8)));
typedef float  f32x4  __attribute__((ext_vector_type(4)));

#define NPOS   225          // 15*15 valid positions
#define NT     15           // row-tiles; p' = i*16 + j (j<15 valid)
#define ROWP   136          // padded LDS row stride in ushorts (272B; 68 dw, odd*4 -> uniform banks)
#define A_ROWS 289          // 17*17 haloed
#define B_ROWS 241          // 240 p' rows + 1 guard
#define A_ELEMS (A_ROWS*ROWP)            // 39304 u16
#define B_ELEMS (B_ROWS*ROWP)            // 32776 u16
#define LDS_BYTES ((A_ELEMS + B_ELEMS)*2)  // 144160 B < 160 KiB
#define RSTRIDE17 (17*ROWP)              // 2312

// ---- workspace layout ----
// floats [0..768): dconv0 weights [k=c*3+t][s_o] (o-dim stored-order, perm'd)
// floats [768..896): dconv0 bias, perm'd
// then bf16 (u16) region, offsets in u16 units:
#define WA_PER_L 49152      // per dconv layer: [og 2][tap 3][ot 4][kb 4][lane 64][8]
#define WP_OFF   (4*WA_PER_L)          // 196608 ; 6 x [og2 2][ot 4][kb 4][64][8]
#define WP_PER   16384
#define WF_OFF   (WP_OFF + 6*WP_PER)   // 294912 ; [4 ot][4 kb][64][8]
#define W_U16_TOTAL (WF_OFF + 8192)    // 303104

// storage<->logical channel permutation: swap bits[5:4] and [3:2]; self-inverse
__host__ __device__ __forceinline__ int permc(int c){
  return (c & ~0x3C) | (((c >> 2) & 3) << 4) | (((c >> 4) & 3) << 2);
}

__device__ __forceinline__ float bflo(u32 q){ return __uint_as_float(q << 16); }
__device__ __forceinline__ float bfhi(u32 q){ return __uint_as_float(q & 0xffff0000u); }
__device__ __forceinline__ u16 f2bf(float f){
  u32 u = __float_as_uint(f);
  return (u16)((u + 0x7fffu + ((u >> 16) & 1u)) >> 16);   // RNE (prep kernel only)
}
__device__ __forceinline__ u32 packbf(float a, float b){
  union { __bf16 h[2]; u32 u; } r;
  r.h[0] = (__bf16)a; r.h[1] = (__bf16)b;   // native cast -> v_cvt_pk_bf16_f32
  return r.u;
}
__device__ __forceinline__ float silu_f(float x){
  return x * __builtin_amdgcn_rcpf(1.f + __expf(-x));
}
__device__ __forceinline__ f32x4 mfma16(bf16x8 a, bf16x8 b, f32x4 c){
  return __builtin_amdgcn_mfma_f32_16x16x32_bf16(a, b, c, 0, 0, 0);
}

// ---- weight prep: perm'd transposes; all k-dims use permc so kernel addressing is linear ----
__global__ void prep_w(const float* __restrict__ d0w, const float* __restrict__ d0b,
                       const float* __restrict__ rdw,
                       const float* __restrict__ rpw, const float* __restrict__ c1w,
                       const float* __restrict__ c2w, const float* __restrict__ fw,
                       float* __restrict__ ws)
{
  u16* wsb = (u16*)(ws + 896);
  const int total = 896 + W_U16_TOTAL;
  for (int idx = blockIdx.x*blockDim.x + threadIdx.x; idx < total; idx += gridDim.x*blockDim.x){
    if (idx < 768){                      // dconv0: ws[k*128+s] = w[perm(s)][k]
      int k = idx >> 7, s = idx & 127;
      ws[idx] = d0w[permc(s)*6 + k];
      continue;
    }
    if (idx < 896){                      // dconv0 bias perm'd
      int s = idx - 768;
      ws[idx] = d0b[permc(s)];
      continue;
    }
    int e = idx - 896;
    float v;
    if (e < WP_OFF){                     // res dconv frags [og][tap][ot][kb][lane][8]
      int L = e / WA_PER_L, r = e % WA_PER_L;
      int og = r / 24576; int r1 = r - og*24576;
      int tap = r1 >> 13; int r2 = r1 & 8191;
      int ot = r2 >> 11, kb = (r2 >> 9) & 3, l = (r2 >> 3) & 63, j = r2 & 7;
      int o = (og*4 + ot)*16 + (l & 15);
      int ks = kb*32 + ((l >> 4) << 3) + j;
      v = rdw[((L*128 + o)*128 + permc(ks))*3 + tap];
    } else if (e < WF_OFF){              // pointwise frags [og2][ot][kb][lane][8]
      int t2 = e - WP_OFF;
      int i = t2 / WP_PER, r = t2 % WP_PER;
      int og2 = r >> 13;
      int ot = (r >> 11) & 3, kb = (r >> 9) & 3, l = (r >> 3) & 63, j = r & 7;
      int o = (og2*4 + ot)*16 + (l & 15);
      int ks = kb*32 + ((l >> 4) << 3) + j;
      v = (i < 4) ? rpw[(i*128 + o)*128 + permc(ks)]
        : (i == 4) ? c1w[o*128 + permc(ks)] : c2w[o*128 + permc(ks)];
    } else {                             // final frags [ot][kb][lane][8]
      int e2 = e - WF_OFF;
      int ot = e2 >> 11, kb = (e2 >> 9) & 3, l = (e2 >> 3) & 63, j = e2 & 7;
      int o = ot*16 + (l & 15);
      int ks = kb*32 + ((l >> 4) << 3) + j;
      v = fw[o*128 + permc(ks)];
    }
    wsb[e] = f2bf(v);
  }
}

// pack 2 accs (8 ch, stored-contiguous) into one uint4 after silu
__device__ __forceinline__ uint4 pack_silu2(const f32x4& a, const f32x4& b){
  uint4 q;
  q.x = packbf(silu_f(a[0]), silu_f(a[1]));
  q.y = packbf(silu_f(a[2]), silu_f(a[3]));
  q.z = packbf(silu_f(b[0]), silu_f(b[1]));
  q.w = packbf(silu_f(b[2]), silu_f(b[3]));
  return q;
}

// ---- directional conv 128->128 via MFMA, tap-outer, 4 o-tiles/wave ----
// wave owns o-tiles [4og,4og+4) (64 ch) and NTL row-tiles starting at T0
template<int NTL>
__device__ __forceinline__ void dconv_mfma(const u16* __restrict__ As, u16* __restrict__ Bs,
    const u16* __restrict__ wloc, const float* __restrict__ bias,
    int lane, int og, int T0, int off0, int off2)
{
  const int col = lane & 15, kg = lane >> 4, koff = kg*8;
  f32x4 acc[4][NTL];
  #pragma unroll
  for (int ot=0; ot<4; ++ot){
    f32x4 bz = *(const f32x4*)(bias + og*64 + ot*16 + kg*4);
    #pragma unroll
    for (int t=0;t<NTL;++t) acc[ot][t] = bz;
  }
  const int c1 = (col+1)*ROWP + koff;
  #pragma unroll 1
  for (int tap=0; tap<3; ++tap){
    const int offr = (tap==0) ? off0 : (tap==1) ? 0 : off2;
    bf16x8 w[4][4];
    #pragma unroll
    for (int ot=0; ot<4; ++ot)
      #pragma unroll
      for (int kb=0; kb<4; ++kb)
        w[ot][kb] = *(const bf16x8*)(wloc + tap*8192 + ot*2048 + kb*512 + lane*8);
    #pragma unroll
    for (int t=0; t<NTL; ++t){
      const u16* s = As + (T0+t+1)*RSTRIDE17 + c1 + offr;
      __builtin_amdgcn_s_setprio(1);
      #pragma unroll
      for (int kb=0; kb<4; ++kb){
        bf16x8 v = *(const bf16x8*)(s + kb*32);
        acc[0][t] = mfma16(w[0][kb], v, acc[0][t]);
        acc[1][t] = mfma16(w[1][kb], v, acc[1][t]);
        acc[2][t] = mfma16(w[2][kb], v, acc[2][t]);
        acc[3][t] = mfma16(w[3][kb], v, acc[3][t]);
      }
      __builtin_amdgcn_s_setprio(0);
    }
  }
  if (col < 15){
    #pragma unroll
    for (int t=0;t<NTL;++t){
      // stored layout: s = og*64 + kg*16 + ot*4 + r -> lane's 16 ch contiguous (32B)
      u16* dp = Bs + ((T0+t)*16+col)*ROWP + og*64 + kg*16;
      uint4 q0 = pack_silu2(acc[0][t], acc[1][t]);
      uint4 q1 = pack_silu2(acc[2][t], acc[3][t]);
      *(uint4*)dp = q0;
      *(uint4*)(dp+8) = q1;
    }
  }
}

// ---- pointwise 128->128 via MFMA; wave owns 4 o-tiles (64 ch), tiles [T0,T1) ----
template<bool SRC_HALO, bool DST_HALO, bool RESID>
__device__ __forceinline__ void pw_mfma(const u16* __restrict__ src, u16* __restrict__ dst,
    const u16* __restrict__ wloc, const float* __restrict__ bias,
    int lane, int og2, int T0, int T1)
{
  const int col = lane & 15, kg = lane >> 4, koff = kg*8;
  bf16x8 wp[4][4];
  #pragma unroll
  for (int ot=0; ot<4; ++ot)
    #pragma unroll
    for (int kb=0; kb<4; ++kb)
      wp[ot][kb] = *(const bf16x8*)(wloc + og2*8192 + ot*2048 + kb*512 + lane*8);
  f32x4 bz[4];
  #pragma unroll
  for (int ot=0; ot<4; ++ot) bz[ot] = *(const f32x4*)(bias + og2*64 + ot*16 + kg*4);
  const int c1 = (col+1)*ROWP;
  #pragma unroll 2
  for (int tile=T0; tile<T1; ++tile){
    const int rh = (tile+1)*RSTRIDE17 + c1;
    const int rc = (tile*16+col)*ROWP;
    const u16* S = src + (SRC_HALO ? rh : rc) + koff;
    f32x4 a0 = bz[0], a1 = bz[1], a2 = bz[2], a3 = bz[3];
    __builtin_amdgcn_s_setprio(1);
    #pragma unroll
    for (int kb=0; kb<4; ++kb){
      bf16x8 v = *(const bf16x8*)(S + kb*32);
      a0 = mfma16(wp[0][kb], v, a0);
      a1 = mfma16(wp[1][kb], v, a1);
      a2 = mfma16(wp[2][kb], v, a2);
      a3 = mfma16(wp[3][kb], v, a3);
    }
    __builtin_amdgcn_s_setprio(0);
    if (col < 15){
      u16* dp = dst + (DST_HALO ? rh : rc) + og2*64 + kg*16;
      float s0 = silu_f(a0[0]), s1 = silu_f(a0[1]), s2 = silu_f(a0[2]), s3 = silu_f(a0[3]);
      float s4 = silu_f(a1[0]), s5 = silu_f(a1[1]), s6 = silu_f(a1[2]), s7 = silu_f(a1[3]);
      float s8 = silu_f(a2[0]), s9 = silu_f(a2[1]), sa = silu_f(a2[2]), sb = silu_f(a2[3]);
      float sc = silu_f(a3[0]), sd = silu_f(a3[1]), se = silu_f(a3[2]), sf = silu_f(a3[3]);
      if (RESID){
        uint4 r0 = *(const uint4*)dp;
        uint4 r1 = *(const uint4*)(dp+8);
        s0 += bflo(r0.x); s1 += bfhi(r0.x); s2 += bflo(r0.y); s3 += bfhi(r0.y);
        s4 += bflo(r0.z); s5 += bfhi(r0.z); s6 += bflo(r0.w); s7 += bfhi(r0.w);
        s8 += bflo(r1.x); s9 += bfhi(r1.x); sa += bflo(r1.y); sb += bfhi(r1.y);
        sc += bflo(r1.z); sd += bfhi(r1.z); se += bflo(r1.w); sf += bfhi(r1.w);
      }
      uint4 q0, q1;
      q0.x = packbf(s0, s1); q0.y = packbf(s2, s3);
      q0.z = packbf(s4, s5); q0.w = packbf(s6, s7);
      q1.x = packbf(s8, s9); q1.y = packbf(sa, sb);
      q1.z = packbf(sc, sd); q1.w = packbf(se, sf);
      *(uint4*)dp = q0;
      *(uint4*)(dp+8) = q1;
    }
  }
}

// ---- final 1x1 128->64; wave owns 2 o-tiles (32 ch), tiles [T0,T1) ----
__device__ __forceinline__ void fin_mfma(const u16* __restrict__ As,
    const u16* __restrict__ wloc, const float* __restrict__ bias,
    float* __restrict__ out, int lane, int ogf, int T0, int T1, int bd)
{
  const int col = lane & 15, kg = lane >> 4, koff = kg*8;
  bf16x8 wf[2][4];
  #pragma unroll
  for (int ot=0; ot<2; ++ot)
    #pragma unroll
    for (int kb=0; kb<4; ++kb)
      wf[ot][kb] = *(const bf16x8*)(wloc + (ogf*2+ot)*2048 + kb*512 + lane*8);
  f32x4 bz0 = *(const f32x4*)(bias + ogf*32 + kg*4);
  f32x4 bz1 = *(const f32x4*)(bias + ogf*32 + 16 + kg*4);
  const int c1 = (col+1)*ROWP;
  #pragma unroll 1
  for (int tile=T0; tile<T1; ++tile){
    const u16* S = As + (tile+1)*RSTRIDE17 + c1 + koff;
    f32x4 a0 = bz0, a1 = bz1;
    __builtin_amdgcn_s_setprio(1);
    #pragma unroll
    for (int kb=0; kb<4; ++kb){
      bf16x8 v = *(const bf16x8*)(S + kb*32);
      a0 = mfma16(wf[0][kb], v, a0);
      a1 = mfma16(wf[1][kb], v, a1);
    }
    __builtin_amdgcn_s_setprio(0);
    if (col < 15){
      float* op = out + ((size_t)(bd*64 + ogf*32 + kg*4))*NPOS + tile*15 + col;
      op[0]      = a0[0];
      op[NPOS]   = a0[1];
      op[2*NPOS] = a0[2];
      op[3*NPOS] = a0[3];
      float* oq = op + 16*NPOS;
      oq[0]      = a1[0];
      oq[NPOS]   = a1[1];
      oq[2*NPOS] = a1[2];
      oq[3*NPOS] = a1[3];
    }
  }
}

__global__ void __launch_bounds__(768, 3)   // 12 waves, 1 block/CU -> 3 waves/SIMD
mix9_main(const float* __restrict__ x,
          const float* __restrict__ b_rd,
          const float* __restrict__ b_rp,
          const float* __restrict__ b_c1,
          const float* __restrict__ b_c2,
          const float* __restrict__ b_fin,
          const float* __restrict__ wt,
          float* __restrict__ out)
{
  extern __shared__ u16 sm[];
  u16* As = sm;              // [289][136] haloed bf16 activations (stored-perm'd ch), zero halo
  u16* Bs = sm + A_ELEMS;    // [241][136] compact p'-row scratch (stored-perm'd ch)

  const int blk  = blockIdx.x;
  const int b    = blk >> 2, d = blk & 3;
  const int tid  = threadIdx.x;
  const int wave = __builtin_amdgcn_readfirstlane(tid >> 6);   // 0..11
  const int lane = tid & 63;

  // 12-wave split: 2 o-groups x 6 position groups; tiles {3,3,3,2,2,2}
  const int og   = (wave >= 6) ? 1 : 0;
  const int pg   = wave - og*6;                 // 0..5
  const int T0p  = (pg < 3) ? pg*3 : 9 + (pg-3)*2;
  const int T1p  = T0p + ((pg < 3) ? 3 : 2);

  const int DI0[4] = {0,-1, 1,-1}, DJ0[4] = {-1, 0,-1,-1};
  const int DI2[4] = {0, 1,-1, 1}, DJ2[4] = { 1, 0, 1, 1};
  const int di0 = DI0[d], dj0 = DJ0[d], di2 = DI2[d], dj2 = DJ2[d];
  const int off0 = (di0*17 + dj0)*ROWP;
  const int off2 = (di2*17 + dj2)*ROWP;

  // zero haloed A; stage input image into B-region as fp32
  for (int k2 = tid; k2 < A_ELEMS; k2 += 768) As[k2] = 0;
  float* xs = (float*)Bs;          // 450 floats
  for (int k2 = tid; k2 < 2*NPOS; k2 += 768) xs[k2] = x[b*(2*NPOS) + k2];
  __syncthreads();

  // ---- dconv0: 2 -> 128 (tiny K: plain VALU, fp32 weights, stored-order o) -> A ----
  if (wave < 8){
    const float* b0p = wt + 768;
    const int ob = wave * 16;
    #pragma unroll 1
    for (int pb = 0; pb < 4; ++pb){
      int pp = pb*64 + lane;           // p' = i*16 + j
      int i = pp >> 4, j = pp & 15;
      if (i >= 15 || j >= 15) continue;
      float acc[16];
      #pragma unroll
      for (int oo=0;oo<16;++oo) acc[oo] = b0p[ob+oo];
      #pragma unroll
      for (int c=0;c<2;++c){
        int i0=i+di0, j0=j+dj0, i2=i+di2, j2=j+dj2;
        float x0 = ((unsigned)i0<15u && (unsigned)j0<15u) ? xs[c*NPOS + i0*15 + j0] : 0.f;
        float x1 = xs[c*NPOS + i*15 + j];
        float x2 = ((unsigned)i2<15u && (unsigned)j2<15u) ? xs[c*NPOS + i2*15 + j2] : 0.f;
        const float* w0r = wt + (c*3+0)*128 + ob;
        const float* w1r = wt + (c*3+1)*128 + ob;
        const float* w2r = wt + (c*3+2)*128 + ob;
        #pragma unroll
        for (int oo=0;oo<16;++oo)
          acc[oo] = fmaf(w0r[oo],x0, fmaf(w1r[oo],x1, fmaf(w2r[oo],x2, acc[oo])));
      }
      u16* dp = As + ((i+1)*17 + (j+1))*ROWP + ob;
      #pragma unroll
      for (int oo=0;oo<16;oo+=2)
        *(u32*)(dp+oo) = packbf(silu_f(acc[oo]), silu_f(acc[oo+1]));
    }
  }
  __syncthreads();

  const u16* wsb = (const u16*)(wt + 896);

  // ---- 4 directional res blocks (MFMA) ----
  #pragma unroll 1
  for (int L = 0; L < 4; ++L){
    if (pg < 3)
      dconv_mfma<3>(As, Bs, wsb + L*WA_PER_L + og*24576, b_rd + L*128, lane, og, pg*3, off0, off2);
    else
      dconv_mfma<2>(As, Bs, wsb + L*WA_PER_L + og*24576, b_rd + L*128, lane, og, 9 + (pg-3)*2, off0, off2);
    __syncthreads();
    pw_mfma<false,true,true>(Bs, As, wsb + WP_OFF + L*WP_PER, b_rp + L*128, lane, og, T0p, T1p);
    __syncthreads();
  }

  // ---- Conv0d res block ----
  pw_mfma<true,false,false>(As, Bs, wsb + WP_OFF + 4*WP_PER, b_c1, lane, og, T0p, T1p);
  __syncthreads();
  pw_mfma<false,true,true>(Bs, As, wsb + WP_OFF + 5*WP_PER, b_c2, lane, og, T0p, T1p);
  __syncthreads();

  // ---- final 1x1: 128 -> 64, MFMA, write global fp32 ----
  fin_mfma(As, wsb + WF_OFF, b_fin, out, lane, og, T0p, T1p, b*4 + d);
}

extern "C" void kernel_launch(void* const* d_in, const int* in_sizes, int n_in,
                              void* d_out, int out_size, void* d_ws, size_t ws_size,
                              hipStream_t stream)
{
  const float* x     = (const float*)d_in[0];
  const float* w_d0  = (const float*)d_in[1];
  const float* b_d0  = (const float*)d_in[2];
  const float* w_rd  = (const float*)d_in[3];
  const float* b_rd  = (const float*)d_in[4];
  const float* w_rp  = (const float*)d_in[5];
  const float* b_rp  = (const float*)d_in[6];
  const float* w_c1  = (const float*)d_in[7];
  const float* b_c1  = (const float*)d_in[8];
  const float* w_c2  = (const float*)d_in[9];
  const float* b_c2  = (const float*)d_in[10];
  const float* w_fin = (const float*)d_in[11];
  const float* b_fin = (const float*)d_in[12];
  float* wt  = (float*)d_ws;
  float* out = (float*)d_out;

  prep_w<<<128, 512, 0, stream>>>(w_d0, b_d0, w_rd, w_rp, w_c1, w_c2, w_fin, wt);

  (void)hipFuncSetAttribute((const void*)mix9_main,
                            hipFuncAttributeMaxDynamicSharedMemorySize, LDS_BYTES);
  mix9_main<<<1024, 768, LDS_BYTES, stream>>>(x, b_rd, b_rp, b_c1, b_c2, b_fin, wt, out);
}